// Round 3
// baseline (326.208 us; speedup 1.0000x reference)
//
#include <hip/hip_runtime.h>
#include <cstdint>
#include <cstddef>

// Problem constants
#define TD 512     // d_model
#define TF 2048    // d_ff
#define NE 8       // experts
#define NT 8192    // tokens (B*S)
#define CAP 17408  // padded assignment slots: 16384 + 8*128

using u16 = unsigned short;
using u32 = unsigned int;

typedef __attribute__((ext_vector_type(8))) __bf16 bf16x8;
typedef __attribute__((ext_vector_type(4))) float f32x4;

__device__ __forceinline__ u16 f2bf(float f) {
  // round-to-nearest-even fp32 -> bf16 (no NaN inputs expected)
  u32 u = __float_as_uint(f);
  u32 r = (u + 0x7fffu + ((u >> 16) & 1u)) >> 16;
  return (u16)r;
}

// async global->LDS, 16B per lane; LDS dest = wave-uniform base + lane*16
__device__ __forceinline__ void load_lds16(const void* g, void* l) {
  __builtin_amdgcn_global_load_lds(
      (const __attribute__((address_space(1))) void*)g,
      (__attribute__((address_space(3))) void*)l, 16, 0, 0);
}

// ---------------- K0: zero output ----------------
__global__ void zero_kernel(float* __restrict__ out) {
  int i = blockIdx.x * 256 + threadIdx.x;
  float4 z = make_float4(0.f, 0.f, 0.f, 0.f);
  *reinterpret_cast<float4*>(out + (size_t)i * 4) = z;
}

// ---------------- K2: transpose + convert weights ----------------
// out[c*R + r] = bf16(in[r*C + c]) per expert (blockIdx.z)
__global__ void transpose_cvt_kernel(const float* __restrict__ in, u16* __restrict__ out,
                                     int R, int C) {
  __shared__ u16 tile[32][33];
  int c0 = blockIdx.x * 32, r0 = blockIdx.y * 32;
  const float* ib = in + (size_t)blockIdx.z * R * C;
  u16* ob = out + (size_t)blockIdx.z * R * C;
  #pragma unroll
  for (int rr = 0; rr < 32; rr += 8) {
    int r = r0 + threadIdx.y + rr;
    int c = c0 + threadIdx.x;
    tile[threadIdx.y + rr][threadIdx.x] = f2bf(ib[(size_t)r * C + c]);
  }
  __syncthreads();
  #pragma unroll
  for (int rr = 0; rr < 32; rr += 8) {
    int oc = c0 + threadIdx.y + rr;   // output row (= input col)
    int orr = r0 + threadIdx.x;       // output col (= input row)
    ob[(size_t)oc * R + orr] = tile[threadIdx.x][threadIdx.y + rr];
  }
}

// ---------------- K3: router (one wave per token, NO atomics) + x->bf16 ----------------
__global__ void router_kernel(const float* __restrict__ x, const float* __restrict__ rw,
                              const float* __restrict__ rb, int2* __restrict__ tokE,
                              float2* __restrict__ tokG, u16* __restrict__ xb) {
  int wv = threadIdx.x >> 6;
  int lane = threadIdx.x & 63;
  int t = blockIdx.x * 4 + wv;
  const float* xr = x + (size_t)t * TD;
  float4 a0 = *reinterpret_cast<const float4*>(xr + lane * 4);
  float4 a1 = *reinterpret_cast<const float4*>(xr + 256 + lane * 4);
  // fused x -> bf16 conversion (coalesced 8B stores)
  {
    u16 o[8];
    o[0] = f2bf(a0.x); o[1] = f2bf(a0.y); o[2] = f2bf(a0.z); o[3] = f2bf(a0.w);
    o[4] = f2bf(a1.x); o[5] = f2bf(a1.y); o[6] = f2bf(a1.z); o[7] = f2bf(a1.w);
    u16* xo = xb + (size_t)t * TD;
    *reinterpret_cast<uint2*>(xo + lane * 4) = *reinterpret_cast<uint2*>(o);
    *reinterpret_cast<uint2*>(xo + 256 + lane * 4) = *reinterpret_cast<uint2*>(o + 4);
  }
  float p[NE];
  #pragma unroll
  for (int e = 0; e < NE; e++) p[e] = 0.f;
  float av[8] = {a0.x, a0.y, a0.z, a0.w, a1.x, a1.y, a1.z, a1.w};
  #pragma unroll
  for (int j = 0; j < 8; j++) {
    int d = (j < 4) ? (lane * 4 + j) : (256 + lane * 4 + j - 4);
    const float* r = rw + (size_t)d * NE;
    #pragma unroll
    for (int e = 0; e < NE; e++) p[e] += av[j] * r[e];
  }
  #pragma unroll
  for (int off = 32; off >= 1; off >>= 1) {
    #pragma unroll
    for (int e = 0; e < NE; e++) p[e] += __shfl_xor(p[e], off);
  }
  if (lane == 0) {
    float l[NE];
    #pragma unroll
    for (int e = 0; e < NE; e++) l[e] = p[e] + rb[e];
    float m = l[0];
    #pragma unroll
    for (int e = 1; e < NE; e++) m = fmaxf(m, l[e]);
    float g[NE];
    #pragma unroll
    for (int e = 0; e < NE; e++) g[e] = __expf(l[e] - m);
    // top-2 by gate (== top-2 by logit); ties -> lower index first (jax top_k)
    int i0 = 0;
    #pragma unroll
    for (int e = 1; e < NE; e++) if (g[e] > g[i0]) i0 = e;
    int i1 = -1;
    #pragma unroll
    for (int e = 0; e < NE; e++) {
      if (e == i0) continue;
      if (i1 < 0 || g[e] > g[i1]) i1 = e;
    }
    float inv = 1.f / (g[i0] + g[i1]);
    tokE[t] = make_int2(i0, i1);
    tokG[t] = make_float2(g[i0] * inv, g[i1] * inv);
  }
}

// ---------------- K4: counts (LDS histogram) + prefix offsets + cursor init ----------------
// single block, 1024 threads
__global__ void count_offsets_kernel(const int2* __restrict__ tokE, int* __restrict__ offs,
                                     int* __restrict__ cursors) {
  __shared__ int hist[NE];
  if (threadIdx.x < NE) {
    hist[threadIdx.x] = 0;
    cursors[threadIdx.x * 16] = 0;   // 64B-padded cursors
  }
  __syncthreads();
  for (int t = threadIdx.x; t < NT; t += 1024) {
    int2 e = tokE[t];
    atomicAdd(&hist[e.x], 1);
    atomicAdd(&hist[e.y], 1);
  }
  __syncthreads();
  if (threadIdx.x == 0) {
    int tot = 0;
    for (int e = 0; e < NE; e++) {
      offs[e] = tot;
      tot += (hist[e] + 127) & ~127;
    }
    offs[NE] = tot;
  }
}

// ---------------- K5: fill slot metadata defaults ----------------
__global__ void fill_kernel(const int* __restrict__ offs, int* __restrict__ tok,
                            float* __restrict__ gate, int* __restrict__ sexp) {
  int s = blockIdx.x * 256 + threadIdx.x;
  int e = NE - 1;
  #pragma unroll
  for (int i = 0; i < NE; i++)
    if (s >= offs[i] && s < offs[i + 1]) e = i;
  sexp[s] = e;
  tok[s] = -1;
  gate[s] = 0.f;
}

// ---------------- K6: scatter assignments (wave-aggregated atomics) ----------------
__global__ void scatter_kernel(const int2* __restrict__ tokE, const float2* __restrict__ tokG,
                               const int* __restrict__ offs, int* __restrict__ cursors,
                               int* __restrict__ tok, float* __restrict__ gate) {
  int t = blockIdx.x * 256 + threadIdx.x;
  int lane = threadIdx.x & 63;
  int2 e = tokE[t];
  float2 g = tokG[t];
  #pragma unroll
  for (int k = 0; k < 2; k++) {
    int ek = k ? e.y : e.x;
    float gk = k ? g.y : g.x;
    #pragma unroll
    for (int ex = 0; ex < NE; ex++) {
      unsigned long long mask = __ballot(ek == ex);
      if (ek == ex) {
        int leader = __ffsll(mask) - 1;
        int rank = __popcll(mask & ((1ull << lane) - 1ull));
        int base = 0;
        if (lane == leader) base = atomicAdd(&cursors[ex * 16], __popcll(mask));
        base = __shfl(base, leader);
        int s = offs[ex] + base + rank;
        tok[s] = t;
        gate[s] = gk;
      }
    }
  }
}

// ---------------- K7: GEMM1  H = relu(x_gather @ W1 + b1), bf16 out ----------------
// grid (CAP/128, TF/128), block 256 (4 waves, 2x2 of 64x64)
// m97-style async staging with XOR-swizzled LDS: LDS[r][c] = G[r][c ^ (r&7)]
// (c = 16B column group). Kills the 16-way ds_read_b128 bank conflicts of the
// unpadded stride-64 layout while keeping the wave-uniform global_load_lds dest.
__global__ __launch_bounds__(256, 4) void gemm1_kernel(
    const u16* __restrict__ xb, const u16* __restrict__ w1t,
    const float* __restrict__ b1, const int* __restrict__ tok,
    const int* __restrict__ sexp, u16* __restrict__ H) {
  __shared__ u16 As[128 * 64];
  __shared__ u16 Bs[128 * 64];
  __shared__ int tokS[128];
  const int tid = threadIdx.x;
  const int s0 = blockIdx.x * 128;
  const int f0 = blockIdx.y * 128;
  const int e = sexp[s0];
  if (tid < 128) {
    int t = tok[s0 + tid];
    tokS[tid] = t < 0 ? 0 : t;  // padding rows read token 0 (result discarded)
  }
  __syncthreads();

  const int lane = tid & 63;
  const int wv = tid >> 6;
  const int srow = lane >> 3;                       // 0..7 within 8-row chunk
  const int scol = (((lane & 7) ^ srow) & 7) * 8;   // swizzled 16B col group
  const int wm = (wv >> 1) * 64;
  const int wn = (wv & 1) * 64;
  const int mrow = lane & 15;
  const int quad = lane >> 4;
  const int rq = mrow & 7;

  f32x4 zero = {0.f, 0.f, 0.f, 0.f};
  f32x4 acc[4][4];
  #pragma unroll
  for (int i = 0; i < 4; i++)
    #pragma unroll
    for (int j = 0; j < 4; j++) acc[i][j] = zero;

  const u16* bbase = w1t + ((size_t)e * TF + f0) * TD;

  for (int k0 = 0; k0 < TD; k0 += 64) {
    if (k0) __syncthreads();
    #pragma unroll
    for (int p = 0; p < 4; p++) {
      int row = wv * 32 + p * 8 + srow;
      load_lds16(xb + (size_t)tokS[row] * TD + k0 + scol, &As[(wv * 32 + p * 8) * 64]);
      load_lds16(bbase + (size_t)row * TD + k0 + scol, &Bs[(wv * 32 + p * 8) * 64]);
    }
    __syncthreads();
    #pragma unroll
    for (int ks = 0; ks < 2; ks++) {
      bf16x8 a[4], b[4];
      #pragma unroll
      for (int i = 0; i < 4; i++)
        a[i] = *reinterpret_cast<const bf16x8*>(
            &As[(wm + i * 16 + mrow) * 64 + ((ks * 4 + quad) ^ rq) * 8]);
      #pragma unroll
      for (int j = 0; j < 4; j++)
        b[j] = *reinterpret_cast<const bf16x8*>(
            &Bs[(wn + j * 16 + mrow) * 64 + ((ks * 4 + quad) ^ rq) * 8]);
      #pragma unroll
      for (int i = 0; i < 4; i++)
        #pragma unroll
        for (int j = 0; j < 4; j++)
          acc[i][j] = __builtin_amdgcn_mfma_f32_16x16x32_bf16(a[i], b[j], acc[i][j], 0, 0, 0);
    }
  }

  float bv[4];
  #pragma unroll
  for (int j = 0; j < 4; j++) bv[j] = b1[e * TF + f0 + wn + j * 16 + mrow];
  #pragma unroll
  for (int i = 0; i < 4; i++) {
    #pragma unroll
    for (int r = 0; r < 4; r++) {
      int row = s0 + wm + i * 16 + quad * 4 + r;
      u16* hrow = H + (size_t)row * TF + f0;
      #pragma unroll
      for (int j = 0; j < 4; j++) {
        float v = acc[i][j][r] + bv[j];
        v = v > 0.f ? v : 0.f;
        hrow[wn + j * 16 + mrow] = f2bf(v);
      }
    }
  }
}

// ---------------- K8: GEMM2  out[tok] += gate * (H @ W2 + b2) ----------------
// grid (CAP/128, TD/128, 2): split-K=2 (z = K-half) for block-count parallelism;
// K-halves accumulate via the atomic epilogue; bias added only by z==0.
__global__ __launch_bounds__(256, 4) void gemm2_kernel(
    const u16* __restrict__ H, const u16* __restrict__ w2t,
    const float* __restrict__ b2, const int* __restrict__ tok,
    const float* __restrict__ gate, const int* __restrict__ sexp,
    float* __restrict__ out) {
  __shared__ u16 As[128 * 64];
  __shared__ u16 Bs[128 * 64];
  __shared__ int tokS[128];
  __shared__ float gateS[128];
  const int tid = threadIdx.x;
  const int s0 = blockIdx.x * 128;
  const int d0 = blockIdx.y * 128;
  const int kz = blockIdx.z;
  const int e = sexp[s0];
  if (tid < 128) {
    tokS[tid] = tok[s0 + tid];
    gateS[tid] = gate[s0 + tid];
  }
  __syncthreads();

  const int lane = tid & 63;
  const int wv = tid >> 6;
  const int srow = lane >> 3;
  const int scol = (((lane & 7) ^ srow) & 7) * 8;
  const int wm = (wv >> 1) * 64;
  const int wn = (wv & 1) * 64;
  const int mrow = lane & 15;
  const int quad = lane >> 4;
  const int rq = mrow & 7;

  f32x4 zero = {0.f, 0.f, 0.f, 0.f};
  f32x4 acc[4][4];
  #pragma unroll
  for (int i = 0; i < 4; i++)
    #pragma unroll
    for (int j = 0; j < 4; j++) acc[i][j] = zero;

  const u16* bbase = w2t + ((size_t)e * TD + d0) * TF;
  const int kbeg = kz * (TF / 2);
  const int kend = kbeg + (TF / 2);

  for (int k0 = kbeg; k0 < kend; k0 += 64) {
    if (k0 != kbeg) __syncthreads();
    #pragma unroll
    for (int p = 0; p < 4; p++) {
      int row = wv * 32 + p * 8 + srow;
      load_lds16(H + (size_t)(s0 + row) * TF + k0 + scol, &As[(wv * 32 + p * 8) * 64]);
      load_lds16(bbase + (size_t)row * TF + k0 + scol, &Bs[(wv * 32 + p * 8) * 64]);
    }
    __syncthreads();
    #pragma unroll
    for (int ks = 0; ks < 2; ks++) {
      bf16x8 a[4], b[4];
      #pragma unroll
      for (int i = 0; i < 4; i++)
        a[i] = *reinterpret_cast<const bf16x8*>(
            &As[(wm + i * 16 + mrow) * 64 + ((ks * 4 + quad) ^ rq) * 8]);
      #pragma unroll
      for (int j = 0; j < 4; j++)
        b[j] = *reinterpret_cast<const bf16x8*>(
            &Bs[(wn + j * 16 + mrow) * 64 + ((ks * 4 + quad) ^ rq) * 8]);
      #pragma unroll
      for (int i = 0; i < 4; i++)
        #pragma unroll
        for (int j = 0; j < 4; j++)
          acc[i][j] = __builtin_amdgcn_mfma_f32_16x16x32_bf16(a[i], b[j], acc[i][j], 0, 0, 0);
    }
  }

  float bv[4];
  #pragma unroll
  for (int j = 0; j < 4; j++)
    bv[j] = (kz == 0) ? b2[e * TD + d0 + wn + j * 16 + mrow] : 0.f;
  #pragma unroll
  for (int i = 0; i < 4; i++) {
    #pragma unroll
    for (int r = 0; r < 4; r++) {
      int rl = wm + i * 16 + quad * 4 + r;
      int t = tokS[rl];
      if (t < 0) continue;
      float g = gateS[rl];
      float* orow = out + (size_t)t * TD + d0;
      #pragma unroll
      for (int j = 0; j < 4; j++) {
        atomicAdd(&orow[wn + j * 16 + mrow], g * (acc[i][j][r] + bv[j]));
      }
    }
  }
}

extern "C" void kernel_launch(void* const* d_in, const int* in_sizes, int n_in,
                              void* d_out, int out_size, void* d_ws, size_t ws_size,
                              hipStream_t stream) {
  const float* x  = (const float*)d_in[0];
  const float* rw = (const float*)d_in[1];
  const float* rb = (const float*)d_in[2];
  const float* w1 = (const float*)d_in[3];
  const float* b1 = (const float*)d_in[4];
  const float* w2 = (const float*)d_in[5];
  const float* b2 = (const float*)d_in[6];
  float* out = (float*)d_out;

  char* w = (char*)d_ws;
  u16* xb   = (u16*)w;            w += (size_t)NT * TD * 2;         // 8 MB
  u16* w1t  = (u16*)w;            w += (size_t)NE * TD * TF * 2;    // 16 MB
  u16* w2t  = (u16*)w;            w += (size_t)NE * TF * TD * 2;    // 16 MB
  u16* H    = (u16*)w;            w += (size_t)CAP * TF * 2;        // 68 MB
  int* tok  = (int*)w;            w += (size_t)CAP * 4;
  float* gate = (float*)w;        w += (size_t)CAP * 4;
  int* sexp = (int*)w;            w += (size_t)CAP * 4;
  int2* tokE = (int2*)w;          w += (size_t)NT * 8;
  float2* tokG = (float2*)w;      w += (size_t)NT * 8;
  int* cursors = (int*)w;         w += 1024;                        // 64B-padded x8
  int* offs = (int*)w;            w += 256;

  // 1. zero output
  zero_kernel<<<dim3((NT * TD) / (256 * 4)), dim3(256), 0, stream>>>(out);
  // 2. transpose+convert w1 [E][D][F] -> w1t [E][F][D]
  transpose_cvt_kernel<<<dim3(TF / 32, TD / 32, NE), dim3(32, 8), 0, stream>>>(w1, w1t, TD, TF);
  // 3. transpose+convert w2 [E][F][D] -> w2t [E][D][F]
  transpose_cvt_kernel<<<dim3(TD / 32, TF / 32, NE), dim3(32, 8), 0, stream>>>(w2, w2t, TF, TD);
  // 4. router (writes tokE/tokG + bf16 x) — no atomics
  router_kernel<<<dim3(NT / 4), dim3(256), 0, stream>>>(x, rw, rb, tokE, tokG, xb);
  // 5. counts + offsets + cursor init (single block)
  count_offsets_kernel<<<dim3(1), dim3(1024), 0, stream>>>(tokE, offs, cursors);
  // 6. fill slot defaults
  fill_kernel<<<dim3(CAP / 256), dim3(256), 0, stream>>>(offs, tok, gate, sexp);
  // 7. scatter assignments (wave-aggregated)
  scatter_kernel<<<dim3(NT / 256), dim3(256), 0, stream>>>(tokE, tokG, offs, cursors, tok, gate);
  // 8. GEMM1
  gemm1_kernel<<<dim3(CAP / 128, TF / 128), dim3(256), 0, stream>>>(xb, w1t, b1, tok, sexp, H);
  // 9. GEMM2 + scatter-add epilogue (split-K=2)
  gemm2_kernel<<<dim3(CAP / 128, TD / 128, 2), dim3(256), 0, stream>>>(H, w2t, b2, tok, gate, sexp, out);
}

// Round 4
// 268.762 us; speedup vs baseline: 1.2137x; 1.2137x over previous
//
#include <hip/hip_runtime.h>
#include <cstdint>
#include <cstddef>

// Problem constants
#define TD 512     // d_model
#define TF 2048    // d_ff
#define NE 8       // experts
#define NT 8192    // tokens (B*S)
#define CAP 17408  // padded assignment slots: 16384 + 8*128

using u16 = unsigned short;
using u32 = unsigned int;

typedef __attribute__((ext_vector_type(8))) __bf16 bf16x8;
typedef __attribute__((ext_vector_type(4))) float f32x4;

__device__ __forceinline__ u16 f2bf(float f) {
  // round-to-nearest-even fp32 -> bf16 (no NaN inputs expected)
  u32 u = __float_as_uint(f);
  u32 r = (u + 0x7fffu + ((u >> 16) & 1u)) >> 16;
  return (u16)r;
}

__device__ __forceinline__ float bf2f(u16 b) {
  return __uint_as_float((u32)b << 16);
}

// async global->LDS, 16B per lane; LDS dest = wave-uniform base + lane*16
__device__ __forceinline__ void load_lds16(const void* g, void* l) {
  __builtin_amdgcn_global_load_lds(
      (const __attribute__((address_space(1))) void*)g,
      (__attribute__((address_space(3))) void*)l, 16, 0, 0);
}

// ---------------- transpose + convert weights ----------------
// out[c*R + r] = bf16(in[r*C + c]) per expert (blockIdx.z)
__global__ void transpose_cvt_kernel(const float* __restrict__ in, u16* __restrict__ out,
                                     int R, int C) {
  __shared__ u16 tile[32][33];
  int c0 = blockIdx.x * 32, r0 = blockIdx.y * 32;
  const float* ib = in + (size_t)blockIdx.z * R * C;
  u16* ob = out + (size_t)blockIdx.z * R * C;
  #pragma unroll
  for (int rr = 0; rr < 32; rr += 8) {
    int r = r0 + threadIdx.y + rr;
    int c = c0 + threadIdx.x;
    tile[threadIdx.y + rr][threadIdx.x] = f2bf(ib[(size_t)r * C + c]);
  }
  __syncthreads();
  #pragma unroll
  for (int rr = 0; rr < 32; rr += 8) {
    int oc = c0 + threadIdx.y + rr;   // output row (= input col)
    int orr = r0 + threadIdx.x;       // output col (= input row)
    ob[(size_t)oc * R + orr] = tile[threadIdx.x][threadIdx.y + rr];
  }
}

// ---------------- router (one wave per token, NO atomics) + x->bf16 ----------------
__global__ void router_kernel(const float* __restrict__ x, const float* __restrict__ rw,
                              const float* __restrict__ rb, int2* __restrict__ tokE,
                              float2* __restrict__ tokG, u16* __restrict__ xb) {
  int wv = threadIdx.x >> 6;
  int lane = threadIdx.x & 63;
  int t = blockIdx.x * 4 + wv;
  const float* xr = x + (size_t)t * TD;
  float4 a0 = *reinterpret_cast<const float4*>(xr + lane * 4);
  float4 a1 = *reinterpret_cast<const float4*>(xr + 256 + lane * 4);
  // fused x -> bf16 conversion (coalesced 8B stores)
  {
    u16 o[8];
    o[0] = f2bf(a0.x); o[1] = f2bf(a0.y); o[2] = f2bf(a0.z); o[3] = f2bf(a0.w);
    o[4] = f2bf(a1.x); o[5] = f2bf(a1.y); o[6] = f2bf(a1.z); o[7] = f2bf(a1.w);
    u16* xo = xb + (size_t)t * TD;
    *reinterpret_cast<uint2*>(xo + lane * 4) = *reinterpret_cast<uint2*>(o);
    *reinterpret_cast<uint2*>(xo + 256 + lane * 4) = *reinterpret_cast<uint2*>(o + 4);
  }
  float p[NE];
  #pragma unroll
  for (int e = 0; e < NE; e++) p[e] = 0.f;
  float av[8] = {a0.x, a0.y, a0.z, a0.w, a1.x, a1.y, a1.z, a1.w};
  #pragma unroll
  for (int j = 0; j < 8; j++) {
    int d = (j < 4) ? (lane * 4 + j) : (256 + lane * 4 + j - 4);
    const float* r = rw + (size_t)d * NE;
    #pragma unroll
    for (int e = 0; e < NE; e++) p[e] += av[j] * r[e];
  }
  #pragma unroll
  for (int off = 32; off >= 1; off >>= 1) {
    #pragma unroll
    for (int e = 0; e < NE; e++) p[e] += __shfl_xor(p[e], off);
  }
  if (lane == 0) {
    float l[NE];
    #pragma unroll
    for (int e = 0; e < NE; e++) l[e] = p[e] + rb[e];
    float m = l[0];
    #pragma unroll
    for (int e = 1; e < NE; e++) m = fmaxf(m, l[e]);
    float g[NE];
    #pragma unroll
    for (int e = 0; e < NE; e++) g[e] = __expf(l[e] - m);
    // top-2 by gate (== top-2 by logit); ties -> lower index first (jax top_k)
    int i0 = 0;
    #pragma unroll
    for (int e = 1; e < NE; e++) if (g[e] > g[i0]) i0 = e;
    int i1 = -1;
    #pragma unroll
    for (int e = 0; e < NE; e++) {
      if (e == i0) continue;
      if (i1 < 0 || g[e] > g[i1]) i1 = e;
    }
    float inv = 1.f / (g[i0] + g[i1]);
    tokE[t] = make_int2(i0, i1);
    tokG[t] = make_float2(g[i0] * inv, g[i1] * inv);
  }
}

// ---------------- counts (LDS histogram) + prefix offsets + cursor init ----------------
// single block, 1024 threads
__global__ void count_offsets_kernel(const int2* __restrict__ tokE, int* __restrict__ offs,
                                     int* __restrict__ cursors) {
  __shared__ int hist[NE];
  if (threadIdx.x < NE) {
    hist[threadIdx.x] = 0;
    cursors[threadIdx.x * 16] = 0;   // 64B-padded cursors
  }
  __syncthreads();
  for (int t = threadIdx.x; t < NT; t += 1024) {
    int2 e = tokE[t];
    atomicAdd(&hist[e.x], 1);
    atomicAdd(&hist[e.y], 1);
  }
  __syncthreads();
  if (threadIdx.x == 0) {
    int tot = 0;
    for (int e = 0; e < NE; e++) {
      offs[e] = tot;
      tot += (hist[e] + 127) & ~127;
    }
    offs[NE] = tot;
  }
}

// ---------------- fill slot metadata defaults ----------------
__global__ void fill_kernel(const int* __restrict__ offs, int* __restrict__ tok,
                            int* __restrict__ sexp) {
  int s = blockIdx.x * 256 + threadIdx.x;
  int e = NE - 1;
  #pragma unroll
  for (int i = 0; i < NE; i++)
    if (s >= offs[i] && s < offs[i + 1]) e = i;
  sexp[s] = e;
  tok[s] = -1;
}

// ---------------- scatter assignments (wave-aggregated atomics) ----------------
__global__ void scatter_kernel(const int2* __restrict__ tokE,
                               const int* __restrict__ offs, int* __restrict__ cursors,
                               int* __restrict__ tok, int* __restrict__ slotOf) {
  int t = blockIdx.x * 256 + threadIdx.x;
  int lane = threadIdx.x & 63;
  int2 e = tokE[t];
  #pragma unroll
  for (int k = 0; k < 2; k++) {
    int ek = k ? e.y : e.x;
    #pragma unroll
    for (int ex = 0; ex < NE; ex++) {
      unsigned long long mask = __ballot(ek == ex);
      if (ek == ex) {
        int leader = __ffsll(mask) - 1;
        int rank = __popcll(mask & ((1ull << lane) - 1ull));
        int base = 0;
        if (lane == leader) base = atomicAdd(&cursors[ex * 16], __popcll(mask));
        base = __shfl(base, leader);
        int s = offs[ex] + base + rank;
        tok[s] = t;
        slotOf[t * 2 + k] = s;
      }
    }
  }
}

// ---------------- GEMM1  H = relu(x_gather @ W1 + b1), bf16 out ----------------
// grid (CAP/128, TF/128), block 256 (4 waves, 2x2 of 64x64)
// m97-style async staging with XOR-swizzled LDS: LDS[r][cg] = G[r][cg ^ (r&7)]
// (cg = 16B column group) — keeps wave-uniform global_load_lds dest, zero conflicts.
__global__ __launch_bounds__(256, 3) void gemm1_kernel(
    const u16* __restrict__ xb, const u16* __restrict__ w1t,
    const float* __restrict__ b1, const int* __restrict__ tok,
    const int* __restrict__ sexp, u16* __restrict__ H) {
  __shared__ u16 As[128 * 64];
  __shared__ u16 Bs[128 * 64];
  __shared__ int tokS[128];
  const int tid = threadIdx.x;
  const int s0 = blockIdx.x * 128;
  const int f0 = blockIdx.y * 128;
  const int e = sexp[s0];
  if (tid < 128) {
    int t = tok[s0 + tid];
    tokS[tid] = t < 0 ? 0 : t;  // padding rows read token 0 (result discarded)
  }
  __syncthreads();

  const int lane = tid & 63;
  const int wv = tid >> 6;
  const int srow = lane >> 3;                       // 0..7 within 8-row chunk
  const int scol = (((lane & 7) ^ srow) & 7) * 8;   // swizzled 16B col group
  const int wm = (wv >> 1) * 64;
  const int wn = (wv & 1) * 64;
  const int mrow = lane & 15;
  const int quad = lane >> 4;
  const int rq = mrow & 7;

  f32x4 zero = {0.f, 0.f, 0.f, 0.f};
  f32x4 acc[4][4];
  #pragma unroll
  for (int i = 0; i < 4; i++)
    #pragma unroll
    for (int j = 0; j < 4; j++) acc[i][j] = zero;

  const u16* bbase = w1t + ((size_t)e * TF + f0) * TD;

  for (int k0 = 0; k0 < TD; k0 += 64) {
    if (k0) __syncthreads();
    #pragma unroll
    for (int p = 0; p < 4; p++) {
      int row = wv * 32 + p * 8 + srow;
      load_lds16(xb + (size_t)tokS[row] * TD + k0 + scol, &As[(wv * 32 + p * 8) * 64]);
      load_lds16(bbase + (size_t)row * TD + k0 + scol, &Bs[(wv * 32 + p * 8) * 64]);
    }
    __syncthreads();
    #pragma unroll
    for (int ks = 0; ks < 2; ks++) {
      bf16x8 a[4], b[4];
      #pragma unroll
      for (int i = 0; i < 4; i++)
        a[i] = *reinterpret_cast<const bf16x8*>(
            &As[(wm + i * 16 + mrow) * 64 + ((ks * 4 + quad) ^ rq) * 8]);
      #pragma unroll
      for (int j = 0; j < 4; j++)
        b[j] = *reinterpret_cast<const bf16x8*>(
            &Bs[(wn + j * 16 + mrow) * 64 + ((ks * 4 + quad) ^ rq) * 8]);
      #pragma unroll
      for (int i = 0; i < 4; i++)
        #pragma unroll
        for (int j = 0; j < 4; j++)
          acc[i][j] = __builtin_amdgcn_mfma_f32_16x16x32_bf16(a[i], b[j], acc[i][j], 0, 0, 0);
    }
  }

  float bv[4];
  #pragma unroll
  for (int j = 0; j < 4; j++) bv[j] = b1[e * TF + f0 + wn + j * 16 + mrow];
  #pragma unroll
  for (int i = 0; i < 4; i++) {
    #pragma unroll
    for (int r = 0; r < 4; r++) {
      int row = s0 + wm + i * 16 + quad * 4 + r;
      u16* hrow = H + (size_t)row * TF + f0;
      #pragma unroll
      for (int j = 0; j < 4; j++) {
        float v = acc[i][j][r] + bv[j];
        v = v > 0.f ? v : 0.f;
        hrow[wn + j * 16 + mrow] = f2bf(v);
      }
    }
  }
}

// ---------------- GEMM2  eout[slot] = H[slot] @ W2 + b2  (bf16, NO atomics) ----------------
// grid (CAP/128, TD/128), block 256
__global__ __launch_bounds__(256, 3) void gemm2_kernel(
    const u16* __restrict__ H, const u16* __restrict__ w2t,
    const float* __restrict__ b2, const int* __restrict__ sexp,
    u16* __restrict__ eout) {
  __shared__ u16 As[128 * 64];
  __shared__ u16 Bs[128 * 64];
  const int tid = threadIdx.x;
  const int s0 = blockIdx.x * 128;
  const int d0 = blockIdx.y * 128;
  const int e = sexp[s0];

  const int lane = tid & 63;
  const int wv = tid >> 6;
  const int srow = lane >> 3;
  const int scol = (((lane & 7) ^ srow) & 7) * 8;
  const int wm = (wv >> 1) * 64;
  const int wn = (wv & 1) * 64;
  const int mrow = lane & 15;
  const int quad = lane >> 4;
  const int rq = mrow & 7;

  f32x4 zero = {0.f, 0.f, 0.f, 0.f};
  f32x4 acc[4][4];
  #pragma unroll
  for (int i = 0; i < 4; i++)
    #pragma unroll
    for (int j = 0; j < 4; j++) acc[i][j] = zero;

  const u16* bbase = w2t + ((size_t)e * TD + d0) * TF;

  for (int k0 = 0; k0 < TF; k0 += 64) {
    if (k0) __syncthreads();
    #pragma unroll
    for (int p = 0; p < 4; p++) {
      int row = wv * 32 + p * 8 + srow;
      load_lds16(H + (size_t)(s0 + row) * TF + k0 + scol, &As[(wv * 32 + p * 8) * 64]);
      load_lds16(bbase + (size_t)row * TF + k0 + scol, &Bs[(wv * 32 + p * 8) * 64]);
    }
    __syncthreads();
    #pragma unroll
    for (int ks = 0; ks < 2; ks++) {
      bf16x8 a[4], b[4];
      #pragma unroll
      for (int i = 0; i < 4; i++)
        a[i] = *reinterpret_cast<const bf16x8*>(
            &As[(wm + i * 16 + mrow) * 64 + ((ks * 4 + quad) ^ rq) * 8]);
      #pragma unroll
      for (int j = 0; j < 4; j++)
        b[j] = *reinterpret_cast<const bf16x8*>(
            &Bs[(wn + j * 16 + mrow) * 64 + ((ks * 4 + quad) ^ rq) * 8]);
      #pragma unroll
      for (int i = 0; i < 4; i++)
        #pragma unroll
        for (int j = 0; j < 4; j++)
          acc[i][j] = __builtin_amdgcn_mfma_f32_16x16x32_bf16(a[i], b[j], acc[i][j], 0, 0, 0);
    }
  }

  float bv[4];
  #pragma unroll
  for (int j = 0; j < 4; j++) bv[j] = b2[e * TD + d0 + wn + j * 16 + mrow];
  #pragma unroll
  for (int i = 0; i < 4; i++) {
    #pragma unroll
    for (int r = 0; r < 4; r++) {
      int row = s0 + wm + i * 16 + quad * 4 + r;
      u16* orow = eout + (size_t)row * TD + d0;
      #pragma unroll
      for (int j = 0; j < 4; j++) {
        orow[wn + j * 16 + mrow] = f2bf(acc[i][j][r] + bv[j]);
      }
    }
  }
}

// ---------------- combine: out[t] = g0*eout[s0] + g1*eout[s1] ----------------
// one wave per token; fully coalesced
__global__ void combine_kernel(const u16* __restrict__ eout, const int* __restrict__ slotOf,
                               const float2* __restrict__ tokG, float* __restrict__ out) {
  int wv = threadIdx.x >> 6;
  int lane = threadIdx.x & 63;
  int t = blockIdx.x * 4 + wv;
  int sA = slotOf[t * 2];
  int sB = slotOf[t * 2 + 1];
  float2 g = tokG[t];
  uint4 ua = *reinterpret_cast<const uint4*>(eout + (size_t)sA * TD + lane * 8);
  uint4 ub = *reinterpret_cast<const uint4*>(eout + (size_t)sB * TD + lane * 8);
  const u16* pa = reinterpret_cast<const u16*>(&ua);
  const u16* pb = reinterpret_cast<const u16*>(&ub);
  float o[8];
  #pragma unroll
  for (int k = 0; k < 8; k++) o[k] = g.x * bf2f(pa[k]) + g.y * bf2f(pb[k]);
  float* od = out + (size_t)t * TD + lane * 8;
  *reinterpret_cast<float4*>(od) = make_float4(o[0], o[1], o[2], o[3]);
  *reinterpret_cast<float4*>(od + 4) = make_float4(o[4], o[5], o[6], o[7]);
}

extern "C" void kernel_launch(void* const* d_in, const int* in_sizes, int n_in,
                              void* d_out, int out_size, void* d_ws, size_t ws_size,
                              hipStream_t stream) {
  const float* x  = (const float*)d_in[0];
  const float* rw = (const float*)d_in[1];
  const float* rb = (const float*)d_in[2];
  const float* w1 = (const float*)d_in[3];
  const float* b1 = (const float*)d_in[4];
  const float* w2 = (const float*)d_in[5];
  const float* b2 = (const float*)d_in[6];
  float* out = (float*)d_out;

  char* w = (char*)d_ws;
  u16* xb   = (u16*)w;            w += (size_t)NT * TD * 2;         // 8 MB
  u16* w1t  = (u16*)w;            w += (size_t)NE * TD * TF * 2;    // 16 MB
  u16* w2t  = (u16*)w;            w += (size_t)NE * TF * TD * 2;    // 16 MB
  u16* H    = (u16*)w;            w += (size_t)CAP * TF * 2;        // 68 MB
  u16* eout = (u16*)w;            w += (size_t)CAP * TD * 2;        // 17 MB
  int* tok  = (int*)w;            w += (size_t)CAP * 4;
  int* sexp = (int*)w;            w += (size_t)CAP * 4;
  int* slotOf = (int*)w;          w += (size_t)NT * 2 * 4;
  int2* tokE = (int2*)w;          w += (size_t)NT * 8;
  float2* tokG = (float2*)w;      w += (size_t)NT * 8;
  int* cursors = (int*)w;         w += 1024;                        // 64B-padded x8
  int* offs = (int*)w;            w += 256;

  // 1. transpose+convert w1 [E][D][F] -> w1t [E][F][D]
  transpose_cvt_kernel<<<dim3(TF / 32, TD / 32, NE), dim3(32, 8), 0, stream>>>(w1, w1t, TD, TF);
  // 2. transpose+convert w2 [E][F][D] -> w2t [E][D][F]
  transpose_cvt_kernel<<<dim3(TD / 32, TF / 32, NE), dim3(32, 8), 0, stream>>>(w2, w2t, TF, TD);
  // 3. router (writes tokE/tokG + bf16 x) — no atomics
  router_kernel<<<dim3(NT / 4), dim3(256), 0, stream>>>(x, rw, rb, tokE, tokG, xb);
  // 4. counts + offsets + cursor init (single block)
  count_offsets_kernel<<<dim3(1), dim3(1024), 0, stream>>>(tokE, offs, cursors);
  // 5. fill slot defaults
  fill_kernel<<<dim3(CAP / 256), dim3(256), 0, stream>>>(offs, tok, sexp);
  // 6. scatter assignments (wave-aggregated) + inverse map
  scatter_kernel<<<dim3(NT / 256), dim3(256), 0, stream>>>(tokE, offs, cursors, tok, slotOf);
  // 7. GEMM1
  gemm1_kernel<<<dim3(CAP / 128, TF / 128), dim3(256), 0, stream>>>(xb, w1t, b1, tok, sexp, H);
  // 8. GEMM2 (non-atomic, per-slot rows)
  gemm2_kernel<<<dim3(CAP / 128, TD / 128), dim3(256), 0, stream>>>(H, w2t, b2, sexp, eout);
  // 9. combine (gather + weighted sum)
  combine_kernel<<<dim3(NT / 4), dim3(256), 0, stream>>>(eout, slotOf, tokG, out);
}

// Round 5
// 268.019 us; speedup vs baseline: 1.2171x; 1.0028x over previous
//
#include <hip/hip_runtime.h>
#include <cstdint>
#include <cstddef>

// Problem constants
#define TD 512     // d_model
#define TF 2048    // d_ff
#define NE 8       // experts
#define NT 8192    // tokens (B*S)
#define CAP 17408  // padded assignment slots: 16384 + 8*128

using u16 = unsigned short;
using u32 = unsigned int;

typedef __attribute__((ext_vector_type(8))) __bf16 bf16x8;
typedef __attribute__((ext_vector_type(4))) float f32x4;

__device__ __forceinline__ u16 f2bf(float f) {
  u32 u = __float_as_uint(f);
  u32 r = (u + 0x7fffu + ((u >> 16) & 1u)) >> 16;
  return (u16)r;
}

__device__ __forceinline__ float bf2f(u16 b) {
  return __uint_as_float((u32)b << 16);
}

// async global->LDS, 16B per lane; LDS dest = wave-uniform base + lane*16
__device__ __forceinline__ void load_lds16(const void* g, void* l) {
  __builtin_amdgcn_global_load_lds(
      (const __attribute__((address_space(1))) void*)g,
      (__attribute__((address_space(3))) void*)l, 16, 0, 0);
}

// ---------------- merged transpose + convert for w1 AND w2 ----------------
__device__ __forceinline__ void transpose_tile(const float* __restrict__ ib,
                                               u16* __restrict__ ob, int R, int C,
                                               int r0, int c0, u16 (*tile)[33]) {
  #pragma unroll
  for (int rr = 0; rr < 32; rr += 8) {
    int r = r0 + threadIdx.y + rr;
    int c = c0 + threadIdx.x;
    tile[threadIdx.y + rr][threadIdx.x] = f2bf(ib[(size_t)r * C + c]);
  }
  __syncthreads();
  #pragma unroll
  for (int rr = 0; rr < 32; rr += 8) {
    int oc = c0 + threadIdx.y + rr;   // output row (= input col)
    int orr = r0 + threadIdx.x;       // output col (= input row)
    ob[(size_t)oc * R + orr] = tile[threadIdx.x][threadIdx.y + rr];
  }
}

// grid (64, 16, 16): z<8 -> expert z of w1 [D][F]; z>=8 -> expert z-8 of w2 [F][D]
__global__ void transpose_both_kernel(const float* __restrict__ w1, u16* __restrict__ w1t,
                                      const float* __restrict__ w2, u16* __restrict__ w2t) {
  __shared__ u16 tile[32][33];
  int z = blockIdx.z;
  if (z < 8) {
    transpose_tile(w1 + (size_t)z * TD * TF, w1t + (size_t)z * TD * TF,
                   TD, TF, blockIdx.y * 32, blockIdx.x * 32, tile);
  } else {
    transpose_tile(w2 + (size_t)(z - 8) * TF * TD, w2t + (size_t)(z - 8) * TF * TD,
                   TF, TD, blockIdx.x * 32, blockIdx.y * 32, tile);
  }
}

// ---------------- router (one wave per token, NO atomics) + x->bf16 ----------------
__global__ void router_kernel(const float* __restrict__ x, const float* __restrict__ rw,
                              const float* __restrict__ rb, int2* __restrict__ tokE,
                              float2* __restrict__ tokG, u16* __restrict__ xb) {
  int wv = threadIdx.x >> 6;
  int lane = threadIdx.x & 63;
  int t = blockIdx.x * 4 + wv;
  const float* xr = x + (size_t)t * TD;
  float4 a0 = *reinterpret_cast<const float4*>(xr + lane * 4);
  float4 a1 = *reinterpret_cast<const float4*>(xr + 256 + lane * 4);
  {
    u16 o[8];
    o[0] = f2bf(a0.x); o[1] = f2bf(a0.y); o[2] = f2bf(a0.z); o[3] = f2bf(a0.w);
    o[4] = f2bf(a1.x); o[5] = f2bf(a1.y); o[6] = f2bf(a1.z); o[7] = f2bf(a1.w);
    u16* xo = xb + (size_t)t * TD;
    *reinterpret_cast<uint2*>(xo + lane * 4) = *reinterpret_cast<uint2*>(o);
    *reinterpret_cast<uint2*>(xo + 256 + lane * 4) = *reinterpret_cast<uint2*>(o + 4);
  }
  float p[NE];
  #pragma unroll
  for (int e = 0; e < NE; e++) p[e] = 0.f;
  float av[8] = {a0.x, a0.y, a0.z, a0.w, a1.x, a1.y, a1.z, a1.w};
  #pragma unroll
  for (int j = 0; j < 8; j++) {
    int d = (j < 4) ? (lane * 4 + j) : (256 + lane * 4 + j - 4);
    const float* r = rw + (size_t)d * NE;
    #pragma unroll
    for (int e = 0; e < NE; e++) p[e] += av[j] * r[e];
  }
  #pragma unroll
  for (int off = 32; off >= 1; off >>= 1) {
    #pragma unroll
    for (int e = 0; e < NE; e++) p[e] += __shfl_xor(p[e], off);
  }
  if (lane == 0) {
    float l[NE];
    #pragma unroll
    for (int e = 0; e < NE; e++) l[e] = p[e] + rb[e];
    float m = l[0];
    #pragma unroll
    for (int e = 1; e < NE; e++) m = fmaxf(m, l[e]);
    float g[NE];
    #pragma unroll
    for (int e = 0; e < NE; e++) g[e] = __expf(l[e] - m);
    int i0 = 0;
    #pragma unroll
    for (int e = 1; e < NE; e++) if (g[e] > g[i0]) i0 = e;
    int i1 = -1;
    #pragma unroll
    for (int e = 0; e < NE; e++) {
      if (e == i0) continue;
      if (i1 < 0 || g[e] > g[i1]) i1 = e;
    }
    float inv = 1.f / (g[i0] + g[i1]);
    tokE[t] = make_int2(i0, i1);
    tokG[t] = make_float2(g[i0] * inv, g[i1] * inv);
  }
}

// ---------------- counts + prefix offsets + cursor init ----------------
__global__ void count_offsets_kernel(const int2* __restrict__ tokE, int* __restrict__ offs,
                                     int* __restrict__ cnt, int* __restrict__ cursors) {
  __shared__ int hist[NE];
  if (threadIdx.x < NE) {
    hist[threadIdx.x] = 0;
    cursors[threadIdx.x * 16] = 0;   // 64B-padded cursors
  }
  __syncthreads();
  for (int t = threadIdx.x; t < NT; t += 1024) {
    int2 e = tokE[t];
    atomicAdd(&hist[e.x], 1);
    atomicAdd(&hist[e.y], 1);
  }
  __syncthreads();
  if (threadIdx.x == 0) {
    int tot = 0;
    for (int e = 0; e < NE; e++) {
      offs[e] = tot;
      cnt[e] = hist[e];
      tot += (hist[e] + 127) & ~127;
    }
    offs[NE] = tot;
  }
}

// ---------------- scatter assignments (wave-aggregated atomics) ----------------
__global__ void scatter_kernel(const int2* __restrict__ tokE,
                               const int* __restrict__ offs, int* __restrict__ cursors,
                               int* __restrict__ tok, int* __restrict__ slotOf) {
  int t = blockIdx.x * 256 + threadIdx.x;
  int lane = threadIdx.x & 63;
  int2 e = tokE[t];
  #pragma unroll
  for (int k = 0; k < 2; k++) {
    int ek = k ? e.y : e.x;
    #pragma unroll
    for (int ex = 0; ex < NE; ex++) {
      unsigned long long mask = __ballot(ek == ex);
      if (ek == ex) {
        int leader = __ffsll(mask) - 1;
        int rank = __popcll(mask & ((1ull << lane) - 1ull));
        int base = 0;
        if (lane == leader) base = atomicAdd(&cursors[ex * 16], __popcll(mask));
        base = __shfl(base, leader);
        int s = offs[ex] + base + rank;
        tok[s] = t;
        slotOf[t * 2 + k] = s;
      }
    }
  }
}

// ---------------- GEMM1  H = relu(x_gather @ W1 + b1), bf16 out ----------------
// grid (CAP/128, TF/128), block 256; XOR-swizzled LDS, async staging
__global__ __launch_bounds__(256, 3) void gemm1_kernel(
    const u16* __restrict__ xb, const u16* __restrict__ w1t,
    const float* __restrict__ b1, const int* __restrict__ tok,
    const int* __restrict__ offs, const int* __restrict__ cnt,
    u16* __restrict__ H) {
  __shared__ u16 As[128 * 64];
  __shared__ u16 Bs[128 * 64];
  __shared__ int tokS[128];
  const int tid = threadIdx.x;
  const int s0 = blockIdx.x * 128;
  const int f0 = blockIdx.y * 128;
  int e = 0;
  #pragma unroll
  for (int i = 1; i <= 7; i++)
    if (s0 >= offs[i]) e = i;
  const int vend = offs[e] + cnt[e];   // slots >= vend within this expert are padding
  if (tid < 128) {
    int s = s0 + tid;
    tokS[tid] = (s < vend) ? tok[s] : 0;  // padding rows read token 0 (discarded)
  }
  __syncthreads();

  const int lane = tid & 63;
  const int wv = tid >> 6;
  const int srow = lane >> 3;
  const int scol = (((lane & 7) ^ srow) & 7) * 8;   // swizzled 16B col group
  const int wm = (wv >> 1) * 64;
  const int wn = (wv & 1) * 64;
  const int mrow = lane & 15;
  const int quad = lane >> 4;
  const int rq = mrow & 7;

  f32x4 zero = {0.f, 0.f, 0.f, 0.f};
  f32x4 acc[4][4];
  #pragma unroll
  for (int i = 0; i < 4; i++)
    #pragma unroll
    for (int j = 0; j < 4; j++) acc[i][j] = zero;

  const u16* bbase = w1t + ((size_t)e * TF + f0) * TD;

  for (int k0 = 0; k0 < TD; k0 += 64) {
    if (k0) __syncthreads();
    #pragma unroll
    for (int p = 0; p < 4; p++) {
      int row = wv * 32 + p * 8 + srow;
      load_lds16(xb + (size_t)tokS[row] * TD + k0 + scol, &As[(wv * 32 + p * 8) * 64]);
      load_lds16(bbase + (size_t)row * TD + k0 + scol, &Bs[(wv * 32 + p * 8) * 64]);
    }
    __syncthreads();
    #pragma unroll
    for (int ks = 0; ks < 2; ks++) {
      bf16x8 a[4], b[4];
      #pragma unroll
      for (int i = 0; i < 4; i++)
        a[i] = *reinterpret_cast<const bf16x8*>(
            &As[(wm + i * 16 + mrow) * 64 + ((ks * 4 + quad) ^ rq) * 8]);
      #pragma unroll
      for (int j = 0; j < 4; j++)
        b[j] = *reinterpret_cast<const bf16x8*>(
            &Bs[(wn + j * 16 + mrow) * 64 + ((ks * 4 + quad) ^ rq) * 8]);
      #pragma unroll
      for (int i = 0; i < 4; i++)
        #pragma unroll
        for (int j = 0; j < 4; j++)
          acc[i][j] = __builtin_amdgcn_mfma_f32_16x16x32_bf16(a[i], b[j], acc[i][j], 0, 0, 0);
    }
  }

  float bv[4];
  #pragma unroll
  for (int j = 0; j < 4; j++) bv[j] = b1[e * TF + f0 + wn + j * 16 + mrow];
  #pragma unroll
  for (int i = 0; i < 4; i++) {
    #pragma unroll
    for (int r = 0; r < 4; r++) {
      int row = s0 + wm + i * 16 + quad * 4 + r;
      u16* hrow = H + (size_t)row * TF + f0;
      #pragma unroll
      for (int j = 0; j < 4; j++) {
        float v = acc[i][j][r] + bv[j];
        v = v > 0.f ? v : 0.f;
        hrow[wn + j * 16 + mrow] = f2bf(v);
      }
    }
  }
}

// ---------------- GEMM2  eoutP[z][slot] = H[slot, half z] @ W2[half z] (+ b2 if z==0) ----------------
// grid (TD/128, CAP/128, 2): split-K=2, non-atomic bf16 partials; d-tile fastest for H locality
__global__ __launch_bounds__(256, 3) void gemm2_kernel(
    const u16* __restrict__ H, const u16* __restrict__ w2t,
    const float* __restrict__ b2, const int* __restrict__ offs,
    u16* __restrict__ eoutP) {
  __shared__ u16 As[128 * 64];
  __shared__ u16 Bs[128 * 64];
  const int tid = threadIdx.x;
  const int d0 = blockIdx.x * 128;
  const int s0 = blockIdx.y * 128;
  const int kz = blockIdx.z;
  int e = 0;
  #pragma unroll
  for (int i = 1; i <= 7; i++)
    if (s0 >= offs[i]) e = i;

  const int lane = tid & 63;
  const int wv = tid >> 6;
  const int srow = lane >> 3;
  const int scol = (((lane & 7) ^ srow) & 7) * 8;
  const int wm = (wv >> 1) * 64;
  const int wn = (wv & 1) * 64;
  const int mrow = lane & 15;
  const int quad = lane >> 4;
  const int rq = mrow & 7;

  f32x4 zero = {0.f, 0.f, 0.f, 0.f};
  f32x4 acc[4][4];
  #pragma unroll
  for (int i = 0; i < 4; i++)
    #pragma unroll
    for (int j = 0; j < 4; j++) acc[i][j] = zero;

  const u16* bbase = w2t + ((size_t)e * TD + d0) * TF;
  const int kbeg = kz * (TF / 2);
  const int kend = kbeg + (TF / 2);

  for (int k0 = kbeg; k0 < kend; k0 += 64) {
    if (k0 != kbeg) __syncthreads();
    #pragma unroll
    for (int p = 0; p < 4; p++) {
      int row = wv * 32 + p * 8 + srow;
      load_lds16(H + (size_t)(s0 + row) * TF + k0 + scol, &As[(wv * 32 + p * 8) * 64]);
      load_lds16(bbase + (size_t)row * TF + k0 + scol, &Bs[(wv * 32 + p * 8) * 64]);
    }
    __syncthreads();
    #pragma unroll
    for (int ks = 0; ks < 2; ks++) {
      bf16x8 a[4], b[4];
      #pragma unroll
      for (int i = 0; i < 4; i++)
        a[i] = *reinterpret_cast<const bf16x8*>(
            &As[(wm + i * 16 + mrow) * 64 + ((ks * 4 + quad) ^ rq) * 8]);
      #pragma unroll
      for (int j = 0; j < 4; j++)
        b[j] = *reinterpret_cast<const bf16x8*>(
            &Bs[(wn + j * 16 + mrow) * 64 + ((ks * 4 + quad) ^ rq) * 8]);
      #pragma unroll
      for (int i = 0; i < 4; i++)
        #pragma unroll
        for (int j = 0; j < 4; j++)
          acc[i][j] = __builtin_amdgcn_mfma_f32_16x16x32_bf16(a[i], b[j], acc[i][j], 0, 0, 0);
    }
  }

  float bv[4];
  #pragma unroll
  for (int j = 0; j < 4; j++)
    bv[j] = (kz == 0) ? b2[e * TD + d0 + wn + j * 16 + mrow] : 0.f;
  u16* base = eoutP + (size_t)kz * CAP * TD;
  #pragma unroll
  for (int i = 0; i < 4; i++) {
    #pragma unroll
    for (int r = 0; r < 4; r++) {
      int row = s0 + wm + i * 16 + quad * 4 + r;
      u16* orow = base + (size_t)row * TD + d0;
      #pragma unroll
      for (int j = 0; j < 4; j++) {
        orow[wn + j * 16 + mrow] = f2bf(acc[i][j][r] + bv[j]);
      }
    }
  }
}

// ---------------- combine: out[t] = gA*(P0[sA]+P1[sA]) + gB*(P0[sB]+P1[sB]) ----------------
__global__ void combine_kernel(const u16* __restrict__ eoutP, const int* __restrict__ slotOf,
                               const float2* __restrict__ tokG, float* __restrict__ out) {
  int wv = threadIdx.x >> 6;
  int lane = threadIdx.x & 63;
  int t = blockIdx.x * 4 + wv;
  int sA = slotOf[t * 2];
  int sB = slotOf[t * 2 + 1];
  float2 g = tokG[t];
  const u16* P0 = eoutP;
  const u16* P1 = eoutP + (size_t)CAP * TD;
  uint4 ua0 = *reinterpret_cast<const uint4*>(P0 + (size_t)sA * TD + lane * 8);
  uint4 ua1 = *reinterpret_cast<const uint4*>(P1 + (size_t)sA * TD + lane * 8);
  uint4 ub0 = *reinterpret_cast<const uint4*>(P0 + (size_t)sB * TD + lane * 8);
  uint4 ub1 = *reinterpret_cast<const uint4*>(P1 + (size_t)sB * TD + lane * 8);
  const u16* pa0 = reinterpret_cast<const u16*>(&ua0);
  const u16* pa1 = reinterpret_cast<const u16*>(&ua1);
  const u16* pb0 = reinterpret_cast<const u16*>(&ub0);
  const u16* pb1 = reinterpret_cast<const u16*>(&ub1);
  float o[8];
  #pragma unroll
  for (int k = 0; k < 8; k++)
    o[k] = g.x * (bf2f(pa0[k]) + bf2f(pa1[k])) + g.y * (bf2f(pb0[k]) + bf2f(pb1[k]));
  float* od = out + (size_t)t * TD + lane * 8;
  *reinterpret_cast<float4*>(od) = make_float4(o[0], o[1], o[2], o[3]);
  *reinterpret_cast<float4*>(od + 4) = make_float4(o[4], o[5], o[6], o[7]);
}

extern "C" void kernel_launch(void* const* d_in, const int* in_sizes, int n_in,
                              void* d_out, int out_size, void* d_ws, size_t ws_size,
                              hipStream_t stream) {
  const float* x  = (const float*)d_in[0];
  const float* rw = (const float*)d_in[1];
  const float* rb = (const float*)d_in[2];
  const float* w1 = (const float*)d_in[3];
  const float* b1 = (const float*)d_in[4];
  const float* w2 = (const float*)d_in[5];
  const float* b2 = (const float*)d_in[6];
  float* out = (float*)d_out;

  char* w = (char*)d_ws;
  u16* xb    = (u16*)w;           w += (size_t)NT * TD * 2;           // 8 MB
  u16* w1t   = (u16*)w;           w += (size_t)NE * TD * TF * 2;      // 16 MB
  u16* w2t   = (u16*)w;           w += (size_t)NE * TF * TD * 2;      // 16 MB
  u16* H     = (u16*)w;           w += (size_t)CAP * TF * 2;          // 68 MB
  u16* eoutP = (u16*)w;           w += (size_t)2 * CAP * TD * 2;      // 35.7 MB
  int* tok   = (int*)w;           w += (size_t)CAP * 4;
  int* slotOf = (int*)w;          w += (size_t)NT * 2 * 4;
  int2* tokE = (int2*)w;          w += (size_t)NT * 8;
  float2* tokG = (float2*)w;      w += (size_t)NT * 8;
  int* cursors = (int*)w;         w += 1024;                          // 64B-padded x8
  int* offs  = (int*)w;           w += 256;
  int* cnt   = (int*)w;           w += 256;

  // 1. transpose+convert w1 and w2 (single launch)
  transpose_both_kernel<<<dim3(64, 16, 16), dim3(32, 8), 0, stream>>>(w1, w1t, w2, w2t);
  // 2. router (writes tokE/tokG + bf16 x) — no atomics
  router_kernel<<<dim3(NT / 4), dim3(256), 0, stream>>>(x, rw, rb, tokE, tokG, xb);
  // 3. counts + offsets + cursor init (single block)
  count_offsets_kernel<<<dim3(1), dim3(1024), 0, stream>>>(tokE, offs, cnt, cursors);
  // 4. scatter assignments (wave-aggregated) + inverse map
  scatter_kernel<<<dim3(NT / 256), dim3(256), 0, stream>>>(tokE, offs, cursors, tok, slotOf);
  // 5. GEMM1
  gemm1_kernel<<<dim3(CAP / 128, TF / 128), dim3(256), 0, stream>>>(xb, w1t, b1, tok, offs, cnt, H);
  // 6. GEMM2 (split-K=2, non-atomic bf16 partials)
  gemm2_kernel<<<dim3(TD / 128, CAP / 128, 2), dim3(256), 0, stream>>>(H, w2t, b2, offs, eoutP);
  // 7. combine (gather + weighted sum of 4 partials)
  combine_kernel<<<dim3(NT / 4), dim3(256), 0, stream>>>(eoutP, slotOf, tokG, out);
}

// Round 6
// 267.228 us; speedup vs baseline: 1.2207x; 1.0030x over previous
//
#include <hip/hip_runtime.h>
#include <cstdint>
#include <cstddef>

// Problem constants
#define TD 512     // d_model
#define TF 2048    // d_ff
#define NE 8       // experts
#define NT 8192    // tokens (B*S)
#define CAP 17408  // padded assignment slots: 16384 + 8*128

using u16 = unsigned short;
using u32 = unsigned int;

typedef __attribute__((ext_vector_type(8))) __bf16 bf16x8;
typedef __attribute__((ext_vector_type(4))) float f32x4;

__device__ __forceinline__ u16 f2bf(float f) {
  u32 u = __float_as_uint(f);
  u32 r = (u + 0x7fffu + ((u >> 16) & 1u)) >> 16;
  return (u16)r;
}

__device__ __forceinline__ float bf2f(u16 b) {
  return __uint_as_float((u32)b << 16);
}

// async global->LDS, 16B per lane; LDS dest = wave-uniform base + lane*16
__device__ __forceinline__ void load_lds16(const void* g, void* l) {
  __builtin_amdgcn_global_load_lds(
      (const __attribute__((address_space(1))) void*)g,
      (__attribute__((address_space(3))) void*)l, 16, 0, 0);
}

// ---------------- 64x64 transpose+convert tile (256 threads) ----------------
// out[c*R + r] = bf16(in[r*C + c]); output rows written as 16 lanes x 8B = 128B lines
__device__ __forceinline__ void transpose64(const float* __restrict__ ib,
                                            u16* __restrict__ ob, int R, int C,
                                            int r0, int c0, u16* tile /*64*68*/) {
  const int tid = threadIdx.x;
  const int l16 = tid & 15;
  const int grp = tid >> 4;   // 0..15
  #pragma unroll
  for (int p = 0; p < 4; p++) {
    int r = p * 16 + grp;
    float4 v = *reinterpret_cast<const float4*>(ib + (size_t)(r0 + r) * C + c0 + l16 * 4);
    u16 o[4] = {f2bf(v.x), f2bf(v.y), f2bf(v.z), f2bf(v.w)};
    *reinterpret_cast<uint2*>(&tile[r * 68 + l16 * 4]) = *reinterpret_cast<uint2*>(o);
  }
  __syncthreads();
  #pragma unroll
  for (int p = 0; p < 4; p++) {
    int c = p * 16 + grp;       // output row (= input col)
    int rr = l16 * 4;           // output col (= input row), 4 at a time
    u16 o[4] = {tile[(rr + 0) * 68 + c], tile[(rr + 1) * 68 + c],
                tile[(rr + 2) * 68 + c], tile[(rr + 3) * 68 + c]};
    *reinterpret_cast<uint2*>(ob + (size_t)(c0 + c) * R + r0 + rr) = *reinterpret_cast<uint2*>(o);
  }
}

// ---------------- prep: router (+x->bf16) fused with both weight transposes ----------------
// blocks [0, NT/4): router, 4 tokens each
// blocks [NT/4, NT/4+2048): w1 transpose tiles; next 2048: w2
__global__ void prep_kernel(const float* __restrict__ x, const float* __restrict__ rw,
                            const float* __restrict__ rb, int2* __restrict__ tokE,
                            float2* __restrict__ tokG, u16* __restrict__ xb,
                            const float* __restrict__ w1, u16* __restrict__ w1t,
                            const float* __restrict__ w2, u16* __restrict__ w2t,
                            int* __restrict__ ghist) {
  __shared__ u16 tile[64 * 68];
  int b = blockIdx.x;
  if (b < NT / 4) {
    if (b == 0 && threadIdx.x < 16) ghist[threadIdx.x] = 0;  // incl. done counter
    int wv = threadIdx.x >> 6;
    int lane = threadIdx.x & 63;
    int t = b * 4 + wv;
    const float* xr = x + (size_t)t * TD;
    float4 a0 = *reinterpret_cast<const float4*>(xr + lane * 4);
    float4 a1 = *reinterpret_cast<const float4*>(xr + 256 + lane * 4);
    {
      u16 o[8];
      o[0] = f2bf(a0.x); o[1] = f2bf(a0.y); o[2] = f2bf(a0.z); o[3] = f2bf(a0.w);
      o[4] = f2bf(a1.x); o[5] = f2bf(a1.y); o[6] = f2bf(a1.z); o[7] = f2bf(a1.w);
      u16* xo = xb + (size_t)t * TD;
      *reinterpret_cast<uint2*>(xo + lane * 4) = *reinterpret_cast<uint2*>(o);
      *reinterpret_cast<uint2*>(xo + 256 + lane * 4) = *reinterpret_cast<uint2*>(o + 4);
    }
    float p[NE];
    #pragma unroll
    for (int e = 0; e < NE; e++) p[e] = 0.f;
    float av[8] = {a0.x, a0.y, a0.z, a0.w, a1.x, a1.y, a1.z, a1.w};
    #pragma unroll
    for (int j = 0; j < 8; j++) {
      int d = (j < 4) ? (lane * 4 + j) : (256 + lane * 4 + j - 4);
      const float* r = rw + (size_t)d * NE;
      #pragma unroll
      for (int e = 0; e < NE; e++) p[e] += av[j] * r[e];
    }
    #pragma unroll
    for (int off = 32; off >= 1; off >>= 1) {
      #pragma unroll
      for (int e = 0; e < NE; e++) p[e] += __shfl_xor(p[e], off);
    }
    if (lane == 0) {
      float l[NE];
      #pragma unroll
      for (int e = 0; e < NE; e++) l[e] = p[e] + rb[e];
      float m = l[0];
      #pragma unroll
      for (int e = 1; e < NE; e++) m = fmaxf(m, l[e]);
      float g[NE];
      #pragma unroll
      for (int e = 0; e < NE; e++) g[e] = __expf(l[e] - m);
      int i0 = 0;
      #pragma unroll
      for (int e = 1; e < NE; e++) if (g[e] > g[i0]) i0 = e;
      int i1 = -1;
      #pragma unroll
      for (int e = 0; e < NE; e++) {
        if (e == i0) continue;
        if (i1 < 0 || g[e] > g[i1]) i1 = e;
      }
      float inv = 1.f / (g[i0] + g[i1]);
      tokE[t] = make_int2(i0, i1);
      tokG[t] = make_float2(g[i0] * inv, g[i1] * inv);
    }
  } else {
    int tb = b - NT / 4;          // 0..4095
    int which = tb >> 11;          // 0: w1, 1: w2
    int idx = tb & 2047;
    int e = idx >> 8;              // 256 tiles per expert
    int tl = idx & 255;
    if (which == 0) {
      // w1 [D][F]: 8 row-tiles x 32 col-tiles
      int rt = tl >> 5, ct = tl & 31;
      transpose64(w1 + (size_t)e * TD * TF, w1t + (size_t)e * TD * TF,
                  TD, TF, rt * 64, ct * 64, tile);
    } else {
      // w2 [F][D]: 32 row-tiles x 8 col-tiles
      int rt = tl >> 3, ct = tl & 7;
      transpose64(w2 + (size_t)e * TF * TD, w2t + (size_t)e * TF * TD,
                  TF, TD, rt * 64, ct * 64, tile);
    }
  }
}

// ---------------- hist: parallel histogram + last-block offsets/cursors ----------------
// 32 blocks x 256 threads, one token each
__global__ void hist_kernel(const int2* __restrict__ tokE, int* __restrict__ ghist,
                            int* __restrict__ offs, int* __restrict__ cnt,
                            int* __restrict__ cursors) {
  __shared__ int h[NE];
  __shared__ int last;
  if (threadIdx.x < NE) h[threadIdx.x] = 0;
  __syncthreads();
  int t = blockIdx.x * 256 + threadIdx.x;
  int2 e = tokE[t];
  atomicAdd(&h[e.x], 1);
  atomicAdd(&h[e.y], 1);
  __syncthreads();
  if (threadIdx.x < NE) atomicAdd(&ghist[threadIdx.x], h[threadIdx.x]);
  __threadfence();
  if (threadIdx.x == 0) last = (atomicAdd(&ghist[15], 1) == 31);
  __syncthreads();
  if (last) {
    if (threadIdx.x == 0) {
      int tot = 0;
      for (int i = 0; i < NE; i++) {
        int hv = atomicAdd(&ghist[i], 0);   // coherent read
        offs[i] = tot;
        cnt[i] = hv;
        tot += (hv + 127) & ~127;
      }
      offs[NE] = tot;
    }
    if (threadIdx.x < NE) cursors[threadIdx.x * 16] = 0;
  }
}

// ---------------- scatter assignments (wave-aggregated atomics) ----------------
__global__ void scatter_kernel(const int2* __restrict__ tokE,
                               const int* __restrict__ offs, int* __restrict__ cursors,
                               int* __restrict__ tok, int* __restrict__ slotOf) {
  int t = blockIdx.x * 256 + threadIdx.x;
  int lane = threadIdx.x & 63;
  int2 e = tokE[t];
  #pragma unroll
  for (int k = 0; k < 2; k++) {
    int ek = k ? e.y : e.x;
    #pragma unroll
    for (int ex = 0; ex < NE; ex++) {
      unsigned long long mask = __ballot(ek == ex);
      if (ek == ex) {
        int leader = __ffsll(mask) - 1;
        int rank = __popcll(mask & ((1ull << lane) - 1ull));
        int base = 0;
        if (lane == leader) base = atomicAdd(&cursors[ex * 16], __popcll(mask));
        base = __shfl(base, leader);
        int s = offs[ex] + base + rank;
        tok[s] = t;
        slotOf[t * 2 + k] = s;
      }
    }
  }
}

// ---------------- GEMM1  H = relu(x_gather @ W1 + b1), bf16 out ----------------
// grid (CAP/128, TF/128), block 256; XOR-swizzled LDS, async staging
__global__ __launch_bounds__(256, 3) void gemm1_kernel(
    const u16* __restrict__ xb, const u16* __restrict__ w1t,
    const float* __restrict__ b1, const int* __restrict__ tok,
    const int* __restrict__ offs, const int* __restrict__ cnt,
    u16* __restrict__ H) {
  __shared__ u16 As[128 * 64];
  __shared__ u16 Bs[128 * 64];
  __shared__ int tokS[128];
  const int tid = threadIdx.x;
  const int s0 = blockIdx.x * 128;
  const int f0 = blockIdx.y * 128;
  int e = 0;
  #pragma unroll
  for (int i = 1; i <= 7; i++)
    if (s0 >= offs[i]) e = i;
  const int vend = offs[e] + cnt[e];
  if (tid < 128) {
    int s = s0 + tid;
    tokS[tid] = (s < vend) ? tok[s] : 0;
  }
  __syncthreads();

  const int lane = tid & 63;
  const int wv = tid >> 6;
  const int srow = lane >> 3;
  const int scol = (((lane & 7) ^ srow) & 7) * 8;   // swizzled 16B col group
  const int wm = (wv >> 1) * 64;
  const int wn = (wv & 1) * 64;
  const int mrow = lane & 15;
  const int quad = lane >> 4;
  const int rq = mrow & 7;

  f32x4 zero = {0.f, 0.f, 0.f, 0.f};
  f32x4 acc[4][4];
  #pragma unroll
  for (int i = 0; i < 4; i++)
    #pragma unroll
    for (int j = 0; j < 4; j++) acc[i][j] = zero;

  const u16* bbase = w1t + ((size_t)e * TF + f0) * TD;

  for (int k0 = 0; k0 < TD; k0 += 64) {
    if (k0) __syncthreads();
    #pragma unroll
    for (int p = 0; p < 4; p++) {
      int row = wv * 32 + p * 8 + srow;
      load_lds16(xb + (size_t)tokS[row] * TD + k0 + scol, &As[(wv * 32 + p * 8) * 64]);
      load_lds16(bbase + (size_t)row * TD + k0 + scol, &Bs[(wv * 32 + p * 8) * 64]);
    }
    __syncthreads();
    #pragma unroll
    for (int ks = 0; ks < 2; ks++) {
      bf16x8 a[4], b[4];
      #pragma unroll
      for (int i = 0; i < 4; i++)
        a[i] = *reinterpret_cast<const bf16x8*>(
            &As[(wm + i * 16 + mrow) * 64 + ((ks * 4 + quad) ^ rq) * 8]);
      #pragma unroll
      for (int j = 0; j < 4; j++)
        b[j] = *reinterpret_cast<const bf16x8*>(
            &Bs[(wn + j * 16 + mrow) * 64 + ((ks * 4 + quad) ^ rq) * 8]);
      #pragma unroll
      for (int i = 0; i < 4; i++)
        #pragma unroll
        for (int j = 0; j < 4; j++)
          acc[i][j] = __builtin_amdgcn_mfma_f32_16x16x32_bf16(a[i], b[j], acc[i][j], 0, 0, 0);
    }
  }

  float bv[4];
  #pragma unroll
  for (int j = 0; j < 4; j++) bv[j] = b1[e * TF + f0 + wn + j * 16 + mrow];
  #pragma unroll
  for (int i = 0; i < 4; i++) {
    #pragma unroll
    for (int r = 0; r < 4; r++) {
      int row = s0 + wm + i * 16 + quad * 4 + r;
      u16* hrow = H + (size_t)row * TF + f0;
      #pragma unroll
      for (int j = 0; j < 4; j++) {
        float v = acc[i][j][r] + bv[j];
        v = v > 0.f ? v : 0.f;
        hrow[wn + j * 16 + mrow] = f2bf(v);
      }
    }
  }
}

// ---------------- GEMM2  eout[slot] = H[slot] @ W2 + b2  (bf16, no atomics, no split-K) ----------------
// grid (CAP/128, TD/128), block 256
__global__ __launch_bounds__(256, 3) void gemm2_kernel(
    const u16* __restrict__ H, const u16* __restrict__ w2t,
    const float* __restrict__ b2, const int* __restrict__ offs,
    u16* __restrict__ eout) {
  __shared__ u16 As[128 * 64];
  __shared__ u16 Bs[128 * 64];
  const int tid = threadIdx.x;
  const int s0 = blockIdx.x * 128;
  const int d0 = blockIdx.y * 128;
  int e = 0;
  #pragma unroll
  for (int i = 1; i <= 7; i++)
    if (s0 >= offs[i]) e = i;

  const int lane = tid & 63;
  const int wv = tid >> 6;
  const int srow = lane >> 3;
  const int scol = (((lane & 7) ^ srow) & 7) * 8;
  const int wm = (wv >> 1) * 64;
  const int wn = (wv & 1) * 64;
  const int mrow = lane & 15;
  const int quad = lane >> 4;
  const int rq = mrow & 7;

  f32x4 zero = {0.f, 0.f, 0.f, 0.f};
  f32x4 acc[4][4];
  #pragma unroll
  for (int i = 0; i < 4; i++)
    #pragma unroll
    for (int j = 0; j < 4; j++) acc[i][j] = zero;

  const u16* bbase = w2t + ((size_t)e * TD + d0) * TF;

  for (int k0 = 0; k0 < TF; k0 += 64) {
    if (k0) __syncthreads();
    #pragma unroll
    for (int p = 0; p < 4; p++) {
      int row = wv * 32 + p * 8 + srow;
      load_lds16(H + (size_t)(s0 + row) * TF + k0 + scol, &As[(wv * 32 + p * 8) * 64]);
      load_lds16(bbase + (size_t)row * TF + k0 + scol, &Bs[(wv * 32 + p * 8) * 64]);
    }
    __syncthreads();
    #pragma unroll
    for (int ks = 0; ks < 2; ks++) {
      bf16x8 a[4], b[4];
      #pragma unroll
      for (int i = 0; i < 4; i++)
        a[i] = *reinterpret_cast<const bf16x8*>(
            &As[(wm + i * 16 + mrow) * 64 + ((ks * 4 + quad) ^ rq) * 8]);
      #pragma unroll
      for (int j = 0; j < 4; j++)
        b[j] = *reinterpret_cast<const bf16x8*>(
            &Bs[(wn + j * 16 + mrow) * 64 + ((ks * 4 + quad) ^ rq) * 8]);
      #pragma unroll
      for (int i = 0; i < 4; i++)
        #pragma unroll
        for (int j = 0; j < 4; j++)
          acc[i][j] = __builtin_amdgcn_mfma_f32_16x16x32_bf16(a[i], b[j], acc[i][j], 0, 0, 0);
    }
  }

  float bv[4];
  #pragma unroll
  for (int j = 0; j < 4; j++) bv[j] = b2[e * TD + d0 + wn + j * 16 + mrow];
  #pragma unroll
  for (int i = 0; i < 4; i++) {
    #pragma unroll
    for (int r = 0; r < 4; r++) {
      int row = s0 + wm + i * 16 + quad * 4 + r;
      u16* orow = eout + (size_t)row * TD + d0;
      #pragma unroll
      for (int j = 0; j < 4; j++) {
        orow[wn + j * 16 + mrow] = f2bf(acc[i][j][r] + bv[j]);
      }
    }
  }
}

// ---------------- combine: out[t] = gA*eout[sA] + gB*eout[sB] ----------------
__global__ void combine_kernel(const u16* __restrict__ eout, const int* __restrict__ slotOf,
                               const float2* __restrict__ tokG, float* __restrict__ out) {
  int wv = threadIdx.x >> 6;
  int lane = threadIdx.x & 63;
  int t = blockIdx.x * 4 + wv;
  int sA = slotOf[t * 2];
  int sB = slotOf[t * 2 + 1];
  float2 g = tokG[t];
  uint4 ua = *reinterpret_cast<const uint4*>(eout + (size_t)sA * TD + lane * 8);
  uint4 ub = *reinterpret_cast<const uint4*>(eout + (size_t)sB * TD + lane * 8);
  const u16* pa = reinterpret_cast<const u16*>(&ua);
  const u16* pb = reinterpret_cast<const u16*>(&ub);
  float o[8];
  #pragma unroll
  for (int k = 0; k < 8; k++) o[k] = g.x * bf2f(pa[k]) + g.y * bf2f(pb[k]);
  float* od = out + (size_t)t * TD + lane * 8;
  *reinterpret_cast<float4*>(od) = make_float4(o[0], o[1], o[2], o[3]);
  *reinterpret_cast<float4*>(od + 4) = make_float4(o[4], o[5], o[6], o[7]);
}

extern "C" void kernel_launch(void* const* d_in, const int* in_sizes, int n_in,
                              void* d_out, int out_size, void* d_ws, size_t ws_size,
                              hipStream_t stream) {
  const float* x  = (const float*)d_in[0];
  const float* rw = (const float*)d_in[1];
  const float* rb = (const float*)d_in[2];
  const float* w1 = (const float*)d_in[3];
  const float* b1 = (const float*)d_in[4];
  const float* w2 = (const float*)d_in[5];
  const float* b2 = (const float*)d_in[6];
  float* out = (float*)d_out;

  char* w = (char*)d_ws;
  u16* xb    = (u16*)w;           w += (size_t)NT * TD * 2;           // 8 MB
  u16* w1t   = (u16*)w;           w += (size_t)NE * TD * TF * 2;      // 16 MB
  u16* w2t   = (u16*)w;           w += (size_t)NE * TF * TD * 2;      // 16 MB
  u16* H     = (u16*)w;           w += (size_t)CAP * TF * 2;          // 68 MB
  u16* eout  = (u16*)w;           w += (size_t)CAP * TD * 2;          // 17 MB
  int* tok   = (int*)w;           w += (size_t)CAP * 4;
  int* slotOf = (int*)w;          w += (size_t)NT * 2 * 4;
  int2* tokE = (int2*)w;          w += (size_t)NT * 8;
  float2* tokG = (float2*)w;      w += (size_t)NT * 8;
  int* ghist = (int*)w;           w += 256;                           // [0..7] hist, [15] done
  int* cursors = (int*)w;         w += 1024;                          // 64B-padded x8
  int* offs  = (int*)w;           w += 256;
  int* cnt   = (int*)w;           w += 256;

  // 1. prep: router + x->bf16 + both weight transposes (fused, overlapped)
  prep_kernel<<<dim3(NT / 4 + 4096), dim3(256), 0, stream>>>(
      x, rw, rb, tokE, tokG, xb, w1, w1t, w2, w2t, ghist);
  // 2. parallel histogram + offsets/cursors (last-block-done)
  hist_kernel<<<dim3(32), dim3(256), 0, stream>>>(tokE, ghist, offs, cnt, cursors);
  // 3. scatter assignments (wave-aggregated) + inverse map
  scatter_kernel<<<dim3(NT / 256), dim3(256), 0, stream>>>(tokE, offs, cursors, tok, slotOf);
  // 4. GEMM1
  gemm1_kernel<<<dim3(CAP / 128, TF / 128), dim3(256), 0, stream>>>(xb, w1t, b1, tok, offs, cnt, H);
  // 5. GEMM2 (no split-K, non-atomic)
  gemm2_kernel<<<dim3(CAP / 128, TD / 128), dim3(256), 0, stream>>>(H, w2t, b2, offs, eout);
  // 6. combine (gather + weighted sum)
  combine_kernel<<<dim3(NT / 4), dim3(256), 0, stream>>>(eout, slotOf, tokG, out);
}